// Round 7
// baseline (436.534 us; speedup 1.0000x reference)
//
#include <hip/hip_runtime.h>
#include <hip/hip_bf16.h>

// MultiHeadAttention: x (8,16,2048,128) fp32, Q=K=V=x per (b,s) head.
// R7: 64 q-rows/wave at KVBLK=32 -> 32 MFMA : 16 LDS-reads per wave-tile
// (LDS pipe demand halves below MFMA demand). Liveness-streamed softmax
// (pack qt0 before qt1) to fit 256-reg budget at launch_bounds(256,2).
// Pre-pass bf16 swizzled images + global_load_lds dbuf retained.

#define NSEQ   2048
#define DIM    128
#define KVBLK  32
#define TILES  (NSEQ / KVBLK)       // 64
#define IMG    (KVBLK * DIM)        // 4096 shorts = 8 KB per image
// EC = (1/512) * log2(e): exp(s/512) == exp2(s*EC); folded into Q.
#define EC (1.44269504088896f / 512.0f)

typedef short s8v __attribute__((ext_vector_type(8)));
typedef float f4   __attribute__((ext_vector_type(4)));
typedef float f16v __attribute__((ext_vector_type(16)));
typedef unsigned int u2 __attribute__((ext_vector_type(2)));
typedef unsigned int u4 __attribute__((ext_vector_type(4)));

typedef __attribute__((address_space(1))) const void glob_t;
typedef __attribute__((address_space(3))) void lds_t;

__device__ __forceinline__ unsigned pk2(float a, float b) {
    union { __hip_bfloat162 h; unsigned u; } c;
    c.h = __float22bfloat162_rn(make_float2(a, b));
    return c.u;
}
// 32-row-image swizzle (bank-optimal; residual ds_read_b128 overhead is inherent)
__device__ __forceinline__ int swz32k(int r) { return ((r & 7) ^ ((r >> 3) & 3)) << 3; }
// 64-row swizzle (fallback kernel only)
__device__ __forceinline__ int swz(int r) { return ((r & 7) ^ ((r >> 3) & 7)) << 3; }

// ---------------- pre-pass: x -> bf16 swizzled 32-row images in ws ----------------
__global__ __launch_bounds__(256)
void prepass(const float* __restrict__ x, short* __restrict__ wsK,
             short* __restrict__ wsV) {
    const int b = blockIdx.x;                   // 4096 blocks, 64 rows each = 2 tiles
    const float* src = x + (size_t)b * (64 * DIM);
    short* dK = wsK + (size_t)b * 2 * IMG;
    short* dV = wsV + (size_t)b * 2 * IMG;
    const int rw = threadIdx.x >> 4;            // rows 4rw..4rw+3 (same 32-row tile)
    const int cg = threadIdx.x & 15;            // cols 8cg..8cg+7
    const int tile = rw >> 3;                   // 0 or 1
    const int ul   = 4 * (rw & 7);              // local u base within tile

    f4 ld[8];
    const float* s = src + (size_t)(4 * rw) * DIM + 8 * cg;
#pragma unroll
    for (int i = 0; i < 4; ++i) {
        ld[2*i]   = *(const f4*)(s + i * DIM);
        ld[2*i+1] = *(const f4*)(s + i * DIM + 4);
    }
#pragma unroll
    for (int i = 0; i < 4; ++i) {               // K image rows (16B stores)
        const int rl = ul + i;
        u4 kv = { pk2(ld[2*i][0],   ld[2*i][1]),   pk2(ld[2*i][2],   ld[2*i][3]),
                  pk2(ld[2*i+1][0], ld[2*i+1][1]), pk2(ld[2*i+1][2], ld[2*i+1][3]) };
        *(u4*)&dK[tile * IMG + ((rl * DIM + 8 * cg) ^ swz32k(rl))] = kv;
    }
#pragma unroll
    for (int j = 0; j < 8; ++j) {               // Vt image rows (8B stores)
        const int d  = 8 * cg + j;
        const int hi = j >> 2, jj = j & 3;
        u2 vv = { pk2(ld[0 + hi][jj], ld[2 + hi][jj]),
                  pk2(ld[4 + hi][jj], ld[6 + hi][jj]) };
        *(u2*)&dV[tile * IMG + ((d * KVBLK + ul) ^ swz32k(d))] = vv;
    }
}

// ---------------- main kernel: 64q/wave, KVBLK=32 dbuf ----------------
__global__ __launch_bounds__(256, 2)
void attn_q64(const float* __restrict__ x, const short* __restrict__ wsK,
              const short* __restrict__ wsV, float* __restrict__ out) {
    const int bid  = blockIdx.x;                    // 1024 blocks
    const int wg   = (bid & 7) * 128 + (bid >> 3);  // XCD swizzle (1024 % 8 == 0)
    const int head = wg >> 3;                       // 8 q-blocks of 256 rows
    const int qb   = wg & 7;

    float* __restrict__ oh = out + (size_t)head * (NSEQ * DIM);
    const short* gK = wsK + (size_t)head * TILES * IMG;
    const short* gV = wsV + (size_t)head * TILES * IMG;

    const int tid  = threadIdx.x;
    const int lane = tid & 63;
    const int wave = tid >> 6;
    const int l31  = lane & 31;
    const int h    = lane >> 5;

    __shared__ __align__(16) short sK [2][IMG];   // 16 KB
    __shared__ __align__(16) short sVt[2][IMG];   // 16 KB

    // ---- Q frags (x * EC, bf16): 2 q-tiles of 32 rows (64 VGPR) ----
    const int qw0 = qb * 256 + wave * 64;
    s8v Qf0[8], Qf1[8];
    {
        const float* xh = x + (size_t)head * (NSEQ * DIM);
#pragma unroll
        for (int qt = 0; qt < 2; ++qt) {
            const float* qp = xh + (size_t)(qw0 + qt * 32 + l31) * DIM + 8 * h;
#pragma unroll
            for (int ks = 0; ks < 8; ++ks) {
                f4 a = *(const f4*)(qp + ks * 16);
                f4 b = *(const f4*)(qp + ks * 16 + 4);
                u4 q = { pk2(a[0] * EC, a[1] * EC), pk2(a[2] * EC, a[3] * EC),
                         pk2(b[0] * EC, b[1] * EC), pk2(b[2] * EC, b[3] * EC) };
                if (qt == 0) Qf0[ks] = *(s8v*)&q; else Qf1[ks] = *(s8v*)&q;
            }
        }
    }

    f16v accO[2][4];
#pragma unroll
    for (int qt = 0; qt < 2; ++qt)
#pragma unroll
        for (int dt = 0; dt < 4; ++dt) accO[qt][dt] = (f16v)(0.f);
    float lsum0 = 0.f, lsum1 = 0.f;

    // per-thread staging offset (16 KB tile: 4 x dwordx4 per thread)
    const int soff = wave * 1024 + lane * 8;
    auto stage = [&](int b, int t) {
        const short* srcK = gK + (size_t)t * IMG + soff;
        const short* srcV = gV + (size_t)t * IMG + soff;
#pragma unroll
        for (int i = 0; i < 2; ++i) {
            __builtin_amdgcn_global_load_lds((glob_t*)(srcK + i * 512),
                (lds_t*)&sK[b][soff + i * 512], 16, 0, 0);
            __builtin_amdgcn_global_load_lds((glob_t*)(srcV + i * 512),
                (lds_t*)&sVt[b][soff + i * 512], 16, 0, 0);
        }
    };

    stage(0, 0);
    __syncthreads();
    int buf = 0;

    const int kbase = l31 * DIM + 8 * h;
    const int ksz   = swz32k(l31);

    for (int t = 0; t < TILES; ++t) {
        if (t + 1 < TILES) stage(buf ^ 1, t + 1);

        // ---- QK^T (swapped): Kf shared by both q-tiles (2 MFMA per read) ----
        f16v accS0 = (f16v)(0.f), accS1 = (f16v)(0.f);
        __builtin_amdgcn_s_setprio(1);
#pragma unroll
        for (int ks = 0; ks < 8; ++ks) {
            s8v Kf = *(const s8v*)&sK[buf][(kbase + ks * 16) ^ ksz];
            accS0 = __builtin_amdgcn_mfma_f32_32x32x16_bf16(Kf, Qf0[ks], accS0, 0, 0, 0);
            accS1 = __builtin_amdgcn_mfma_f32_32x32x16_bf16(Kf, Qf1[ks], accS1, 0, 0, 0);
        }
        __builtin_amdgcn_s_setprio(0);

        // ---- softmax + T12 pack, streamed: qt0 fully, then qt1 (caps liveness) ----
        s8v Pf0[2], Pf1[2];
        {
            float part = 0.f;
#pragma unroll
            for (int r = 0; r < 16; ++r) {
                float v = __builtin_amdgcn_exp2f(accS0[r]);
                accS0[r] = v;
                part += v;
            }
            lsum0 += part;
#pragma unroll
            for (int ksl = 0; ksl < 2; ++ksl) {
                unsigned pa0 = pk2(accS0[8*ksl + 0], accS0[8*ksl + 1]);
                unsigned pa1 = pk2(accS0[8*ksl + 2], accS0[8*ksl + 3]);
                unsigned pb0 = pk2(accS0[8*ksl + 4], accS0[8*ksl + 5]);
                unsigned pb1 = pk2(accS0[8*ksl + 6], accS0[8*ksl + 7]);
                auto t0 = __builtin_amdgcn_permlane32_swap(pa0, pb0, false, false);
                auto t1 = __builtin_amdgcn_permlane32_swap(pa1, pb1, false, false);
                u4 w = { (unsigned)t0[0], (unsigned)t1[0], (unsigned)t0[1], (unsigned)t1[1] };
                Pf0[ksl] = *(s8v*)&w;
            }
        }
        {
            float part = 0.f;
#pragma unroll
            for (int r = 0; r < 16; ++r) {
                float v = __builtin_amdgcn_exp2f(accS1[r]);
                accS1[r] = v;
                part += v;
            }
            lsum1 += part;
#pragma unroll
            for (int ksl = 0; ksl < 2; ++ksl) {
                unsigned pa0 = pk2(accS1[8*ksl + 0], accS1[8*ksl + 1]);
                unsigned pa1 = pk2(accS1[8*ksl + 2], accS1[8*ksl + 3]);
                unsigned pb0 = pk2(accS1[8*ksl + 4], accS1[8*ksl + 5]);
                unsigned pb1 = pk2(accS1[8*ksl + 6], accS1[8*ksl + 7]);
                auto t0 = __builtin_amdgcn_permlane32_swap(pa0, pb0, false, false);
                auto t1 = __builtin_amdgcn_permlane32_swap(pa1, pb1, false, false);
                u4 w = { (unsigned)t0[0], (unsigned)t1[0], (unsigned)t0[1], (unsigned)t1[1] };
                Pf1[ksl] = *(s8v*)&w;
            }
        }

        // ---- PV: Vf shared by both q-tiles (2 MFMA per read) ----
        __builtin_amdgcn_s_setprio(1);
#pragma unroll
        for (int dt = 0; dt < 4; ++dt) {
            const int d    = dt * 32 + l31;
            const int base = d * KVBLK + 8 * h;
            const int sz   = swz32k(d);
#pragma unroll
            for (int ksl = 0; ksl < 2; ++ksl) {
                s8v Vf = *(const s8v*)&sVt[buf][(base + ksl * 16) ^ sz];
                accO[0][dt] = __builtin_amdgcn_mfma_f32_32x32x16_bf16(
                    Pf0[ksl], Vf, accO[0][dt], 0, 0, 0);
                accO[1][dt] = __builtin_amdgcn_mfma_f32_32x32x16_bf16(
                    Pf1[ksl], Vf, accO[1][dt], 0, 0, 0);
            }
        }
        __builtin_amdgcn_s_setprio(0);

        __syncthreads();   // drains DMA (next tile resident); this tile's reads done
        buf ^= 1;
    }

    // ---- epilogue ----
#pragma unroll
    for (int qt = 0; qt < 2; ++qt) {
        const float ls  = qt ? lsum1 : lsum0;
        const float tot = ls + __shfl_xor(ls, 32);
        const float inv = 1.f / tot;
#pragma unroll
        for (int r = 0; r < 16; ++r) {
            const int q      = (r & 3) + 8 * (r >> 2) + 4 * h;
            const float invq = __shfl(inv, q, 32);
            float* op = oh + (size_t)(qw0 + qt * 32 + q) * DIM + l31;
#pragma unroll
            for (int dt = 0; dt < 4; ++dt)
                op[dt * 32] = accO[qt][dt][r] * invq;
        }
    }
}

// ---------------- fallback (ws too small): proven no-ws kernel ----------------
__global__ __launch_bounds__(256, 2)
void attn_fwd_fb(const float* __restrict__ x, float* __restrict__ out) {
    const int bid  = blockIdx.x;
    const int wg   = (bid & 7) * 256 + (bid >> 3);
    const int head = wg >> 4;
    const int qb   = wg & 15;
    const float* __restrict__ xh = x   + (size_t)head * (NSEQ * DIM);
    float* __restrict__       oh = out + (size_t)head * (NSEQ * DIM);
    const int tid  = threadIdx.x;
    const int lane = tid & 63;
    const int wave = tid >> 6;
    const int l31  = lane & 31;
    const int h    = lane >> 5;
    __shared__ __align__(16) short sK [64 * DIM];
    __shared__ __align__(16) short sVt[DIM * 64];
    const int qw0 = qb * 128 + wave * 32;
    s8v Qf[8];
    {
        const float* qp = xh + (size_t)(qw0 + l31) * DIM + 8 * h;
#pragma unroll
        for (int ks = 0; ks < 8; ++ks) {
            f4 a = *(const f4*)(qp + ks * 16);
            f4 b = *(const f4*)(qp + ks * 16 + 4);
            u4 q = { pk2(a[0] * EC, a[1] * EC), pk2(a[2] * EC, a[3] * EC),
                     pk2(b[0] * EC, b[1] * EC), pk2(b[2] * EC, b[3] * EC) };
            Qf[ks] = *(s8v*)&q;
        }
    }
    f16v accO[4];
#pragma unroll
    for (int dt = 0; dt < 4; ++dt) accO[dt] = (f16v)(0.f);
    float lsum = 0.f;
    const int rw = tid >> 4;
    const int cg = tid & 15;
    f4 ld[8];
    {
        const float* s = xh + (size_t)(4 * rw) * DIM + 8 * cg;
#pragma unroll
        for (int i = 0; i < 4; ++i) {
            ld[2*i]   = *(const f4*)(s + i * DIM);
            ld[2*i+1] = *(const f4*)(s + i * DIM + 4);
        }
    }
    for (int kv0 = 0; kv0 < NSEQ; kv0 += 64) {
#pragma unroll
        for (int i = 0; i < 4; ++i) {
            const int r = 4 * rw + i;
            u4 kv = { pk2(ld[2*i][0],   ld[2*i][1]),   pk2(ld[2*i][2],   ld[2*i][3]),
                      pk2(ld[2*i+1][0], ld[2*i+1][1]), pk2(ld[2*i+1][2], ld[2*i+1][3]) };
            *(u4*)&sK[(r * DIM + 8 * cg) ^ swz(r)] = kv;
        }
#pragma unroll
        for (int j = 0; j < 8; ++j) {
            const int d  = 8 * cg + j;
            const int hi = j >> 2, jj = j & 3;
            u2 vv = { pk2(ld[0 + hi][jj], ld[2 + hi][jj]),
                      pk2(ld[4 + hi][jj], ld[6 + hi][jj]) };
            *(u2*)&sVt[(d * 64 + 4 * rw) ^ swz(d)] = vv;
        }
        __syncthreads();
        f16v accS[2];
        accS[0] = (f16v)(0.f); accS[1] = (f16v)(0.f);
        __builtin_amdgcn_s_setprio(1);
#pragma unroll
        for (int ut = 0; ut < 2; ++ut) {
            const int r    = ut * 32 + l31;
            const int base = r * DIM + 8 * h;
            const int sz   = swz(r);
#pragma unroll
            for (int ks = 0; ks < 8; ++ks) {
                s8v Kf = *(const s8v*)&sK[(base + ks * 16) ^ sz];
                accS[ut] = __builtin_amdgcn_mfma_f32_32x32x16_bf16(
                    Kf, Qf[ks], accS[ut], 0, 0, 0);
            }
        }
        __builtin_amdgcn_s_setprio(0);
        if (kv0 + 64 < NSEQ) {
            const float* s = xh + (size_t)(kv0 + 64 + 4 * rw) * DIM + 8 * cg;
#pragma unroll
            for (int i = 0; i < 4; ++i) {
                ld[2*i]   = *(const f4*)(s + i * DIM);
                ld[2*i+1] = *(const f4*)(s + i * DIM + 4);
            }
        }
        float part = 0.f;
#pragma unroll
        for (int ut = 0; ut < 2; ++ut)
#pragma unroll
            for (int r = 0; r < 16; ++r) {
                float v = __builtin_amdgcn_exp2f(accS[ut][r]);
                accS[ut][r] = v;
                part += v;
            }
        lsum += part;
        s8v Pf[4];
#pragma unroll
        for (int ks = 0; ks < 4; ++ks) {
#define PP(f) accS[(f) >> 4][(f) & 15]
            unsigned pa0 = pk2(PP(8*ks + 0), PP(8*ks + 1));
            unsigned pa1 = pk2(PP(8*ks + 2), PP(8*ks + 3));
            unsigned pb0 = pk2(PP(8*ks + 4), PP(8*ks + 5));
            unsigned pb1 = pk2(PP(8*ks + 6), PP(8*ks + 7));
#undef PP
            auto t0 = __builtin_amdgcn_permlane32_swap(pa0, pb0, false, false);
            auto t1 = __builtin_amdgcn_permlane32_swap(pa1, pb1, false, false);
            u4 w = { (unsigned)t0[0], (unsigned)t1[0], (unsigned)t0[1], (unsigned)t1[1] };
            Pf[ks] = *(s8v*)&w;
        }
        __builtin_amdgcn_s_setprio(1);
#pragma unroll
        for (int dt = 0; dt < 4; ++dt) {
            const int d    = dt * 32 + l31;
            const int base = d * 64 + 8 * h;
            const int sz   = swz(d);
#pragma unroll
            for (int ks = 0; ks < 4; ++ks) {
                s8v Vf = *(const s8v*)&sVt[(base + ks * 16) ^ sz];
                accO[dt] = __builtin_amdgcn_mfma_f32_32x32x16_bf16(
                    Pf[ks], Vf, accO[dt], 0, 0, 0);
            }
        }
        __builtin_amdgcn_s_setprio(0);
        __syncthreads();
    }
    const float tot = lsum + __shfl_xor(lsum, 32);
    const float inv = 1.f / tot;
#pragma unroll
    for (int r = 0; r < 16; ++r) {
        const int q      = (r & 3) + 8 * (r >> 2) + 4 * h;
        const float invq = __shfl(inv, q, 32);
        float* op = oh + (size_t)(qw0 + q) * DIM + l31;
#pragma unroll
        for (int dt = 0; dt < 4; ++dt)
            op[dt * 32] = accO[dt][r] * invq;
    }
}

extern "C" void kernel_launch(void* const* d_in, const int* in_sizes, int n_in,
                              void* d_out, int out_size, void* d_ws, size_t ws_size,
                              hipStream_t stream) {
    const float* x = (const float*)d_in[0];
    float* out     = (float*)d_out;
    const size_t perImg = (size_t)128 * TILES * IMG;            // shorts
    const size_t need   = 2 * perImg * sizeof(short);           // 128 MiB
    if (ws_size >= need) {
        short* wsK = (short*)d_ws;
        short* wsV = wsK + perImg;
        hipLaunchKernelGGL(prepass, dim3(4096), dim3(256), 0, stream, x, wsK, wsV);
        hipLaunchKernelGGL(attn_q64, dim3(1024), dim3(256), 0, stream, x, wsK, wsV, out);
    } else {
        hipLaunchKernelGGL(attn_fwd_fb, dim3(2048), dim3(256), 0, stream, x, out);
    }
}

// Round 9
// 363.687 us; speedup vs baseline: 1.2003x; 1.2003x over previous
//
#include <hip/hip_runtime.h>
#include <hip/hip_bf16.h>
#include <utility>

// MultiHeadAttention: x (8,16,2048,128) fp32, Q=K=V=x per (b,s) head.
// R9: R8 with the PV ksl=1 address bug fixed (k-slice offset must be inside
// the XOR-swizzle: (base+16)^sz, not (base^sz)+16 — bits overlap).
// Structure: KVBLK=32 dbuf, 3 blocks/CU, dual QK chains, softmax/PV halves,
// compile-time buffer index.

#define NSEQ   2048
#define DIM    128
#define KVBLK  32
#define TILES  (NSEQ / KVBLK)       // 64
#define IMG    (KVBLK * DIM)        // 4096 shorts = 8 KB per image
// EC = (1/512) * log2(e): exp(s/512) == exp2(s*EC); folded into Q.
#define EC (1.44269504088896f / 512.0f)

typedef short s8v __attribute__((ext_vector_type(8)));
typedef float f4   __attribute__((ext_vector_type(4)));
typedef float f8v  __attribute__((ext_vector_type(8)));
typedef float f16v __attribute__((ext_vector_type(16)));
typedef unsigned int u2 __attribute__((ext_vector_type(2)));
typedef unsigned int u4 __attribute__((ext_vector_type(4)));

typedef __attribute__((address_space(1))) const void glob_t;
typedef __attribute__((address_space(3))) void lds_t;

__device__ __forceinline__ unsigned pk2(float a, float b) {
    union { __hip_bfloat162 h; unsigned u; } c;
    c.h = __float22bfloat162_rn(make_float2(a, b));
    return c.u;
}
// 32-row-image swizzle (bank-optimal; residual ds_read_b128 overhead inherent)
__device__ __forceinline__ int swz32k(int r) { return ((r & 7) ^ ((r >> 3) & 3)) << 3; }
// 64-row swizzle (fallback kernel only)
__device__ __forceinline__ int swz(int r) { return ((r & 7) ^ ((r >> 3) & 7)) << 3; }

// ---------------- pre-pass: x -> bf16 swizzled 32-row images in ws ----------------
__global__ __launch_bounds__(256)
void prepass(const float* __restrict__ x, short* __restrict__ wsK,
             short* __restrict__ wsV) {
    const int b = blockIdx.x;                   // 4096 blocks, 64 rows = 2 tiles
    const float* src = x + (size_t)b * (64 * DIM);
    short* dK = wsK + (size_t)b * 2 * IMG;
    short* dV = wsV + (size_t)b * 2 * IMG;
    const int rw = threadIdx.x >> 4;
    const int cg = threadIdx.x & 15;
    const int tile = rw >> 3;
    const int ul   = 4 * (rw & 7);

    f4 ld[8];
    const float* s = src + (size_t)(4 * rw) * DIM + 8 * cg;
#pragma unroll
    for (int i = 0; i < 4; ++i) {
        ld[2*i]   = *(const f4*)(s + i * DIM);
        ld[2*i+1] = *(const f4*)(s + i * DIM + 4);
    }
#pragma unroll
    for (int i = 0; i < 4; ++i) {               // K image rows (16B stores)
        const int rl = ul + i;
        u4 kv = { pk2(ld[2*i][0],   ld[2*i][1]),   pk2(ld[2*i][2],   ld[2*i][3]),
                  pk2(ld[2*i+1][0], ld[2*i+1][1]), pk2(ld[2*i+1][2], ld[2*i+1][3]) };
        *(u4*)&dK[tile * IMG + ((rl * DIM + 8 * cg) ^ swz32k(rl))] = kv;
    }
#pragma unroll
    for (int j = 0; j < 8; ++j) {               // Vt image rows (8B stores)
        const int d  = 8 * cg + j;
        const int hi = j >> 2, jj = j & 3;
        u2 vv = { pk2(ld[0 + hi][jj], ld[2 + hi][jj]),
                  pk2(ld[4 + hi][jj], ld[6 + hi][jj]) };
        *(u2*)&dV[tile * IMG + ((d * KVBLK + ul) ^ swz32k(d))] = vv;
    }
}

// ---------------- main kernel: 32q/wave, KVBLK=32 dbuf, 3 blocks/CU ----------------
__global__ __launch_bounds__(256, 3)
void attn_k32p(const float* __restrict__ x, const short* __restrict__ wsK,
               const short* __restrict__ wsV, float* __restrict__ out) {
    const int bid  = blockIdx.x;                    // 2048 blocks
    const int wg   = (bid & 7) * 256 + (bid >> 3);  // XCD swizzle (2048 % 8 == 0)
    const int head = wg >> 4;
    const int qb   = wg & 15;

    float* __restrict__ oh = out + (size_t)head * (NSEQ * DIM);
    const short* gK = wsK + (size_t)head * TILES * IMG;
    const short* gV = wsV + (size_t)head * TILES * IMG;

    const int tid  = threadIdx.x;
    const int lane = tid & 63;
    const int wave = tid >> 6;
    const int l31  = lane & 31;
    const int h    = lane >> 5;

    __shared__ __align__(16) short sK [2][IMG];   // 16 KB
    __shared__ __align__(16) short sVt[2][IMG];   // 16 KB

    // ---- Q frags (x * EC, bf16) ----
    const int qw0 = qb * 128 + wave * 32;
    s8v Qf[8];
    {
        const float* qp = x + (size_t)head * (NSEQ * DIM)
                            + (size_t)(qw0 + l31) * DIM + 8 * h;
#pragma unroll
        for (int ks = 0; ks < 8; ++ks) {
            f4 a = *(const f4*)(qp + ks * 16);
            f4 b = *(const f4*)(qp + ks * 16 + 4);
            u4 q = { pk2(a[0] * EC, a[1] * EC), pk2(a[2] * EC, a[3] * EC),
                     pk2(b[0] * EC, b[1] * EC), pk2(b[2] * EC, b[3] * EC) };
            Qf[ks] = *(s8v*)&q;
        }
    }

    f16v accO[4];
#pragma unroll
    for (int dt = 0; dt < 4; ++dt) accO[dt] = (f16v)(0.f);
    float lsum = 0.f;

    const int soff = wave * 1024 + lane * 8;
    auto stage = [&](int b, int t) {
        const short* srcK = gK + (size_t)t * IMG + soff;
        const short* srcV = gV + (size_t)t * IMG + soff;
#pragma unroll
        for (int i = 0; i < 2; ++i) {
            __builtin_amdgcn_global_load_lds((glob_t*)(srcK + i * 512),
                (lds_t*)&sK[b][soff + i * 512], 16, 0, 0);
            __builtin_amdgcn_global_load_lds((glob_t*)(srcV + i * 512),
                (lds_t*)&sVt[b][soff + i * 512], 16, 0, 0);
        }
    };

    stage(0, 0);
    __syncthreads();

    const int kbase = l31 * DIM + 8 * h;
    const int ksz   = swz32k(l31);

    // tile body with compile-time buffer index B
    auto body = [&](auto Bc, int T) {
        constexpr int B = decltype(Bc)::value;
        if (T + 1 < TILES) stage(B ^ 1, T + 1);

        // ---- QK^T: two independent accumulation chains (even/odd ks) ----
        f16v aA = (f16v)(0.f), aB = (f16v)(0.f);
        __builtin_amdgcn_s_setprio(1);
#pragma unroll
        for (int ks = 0; ks < 4; ++ks) {
            s8v Kf0 = *(const s8v*)&sK[B][(kbase + (2 * ks)     * 16) ^ ksz];
            s8v Kf1 = *(const s8v*)&sK[B][(kbase + (2 * ks + 1) * 16) ^ ksz];
            aA = __builtin_amdgcn_mfma_f32_32x32x16_bf16(Kf0, Qf[2*ks],   aA, 0, 0, 0);
            aB = __builtin_amdgcn_mfma_f32_32x32x16_bf16(Kf1, Qf[2*ks+1], aB, 0, 0, 0);
        }
        __builtin_amdgcn_s_setprio(0);

        // ---- softmax half 0 (regs 0..7) -> Pf0 ----
        float part0 = 0.f, part1 = 0.f;
        f8v P0, P1;
#pragma unroll
        for (int r = 0; r < 8; ++r) {
            float v = __builtin_amdgcn_exp2f(aA[r] + aB[r]);
            P0[r] = v; part0 += v;
        }
        s8v Pf0;
        {
            unsigned x0 = pk2(P0[0], P0[1]), x1 = pk2(P0[2], P0[3]);
            unsigned y0 = pk2(P0[4], P0[5]), y1 = pk2(P0[6], P0[7]);
            auto t0 = __builtin_amdgcn_permlane32_swap(x0, y0, false, false);
            auto t1 = __builtin_amdgcn_permlane32_swap(x1, y1, false, false);
            u4 w = { (unsigned)t0[0], (unsigned)t1[0], (unsigned)t0[1], (unsigned)t1[1] };
            Pf0 = *(s8v*)&w;
        }

        // ---- PV ksl=0 (independent of softmax half 1 -> schedulable overlap) ----
        __builtin_amdgcn_s_setprio(1);
#pragma unroll
        for (int dt = 0; dt < 4; ++dt) {
            const int d = dt * 32 + l31;
            s8v Vf = *(const s8v*)&sVt[B][(d * KVBLK + 8 * h) ^ swz32k(d)];
            accO[dt] = __builtin_amdgcn_mfma_f32_32x32x16_bf16(Pf0, Vf, accO[dt], 0, 0, 0);
        }
        __builtin_amdgcn_s_setprio(0);

        // ---- softmax half 1 (regs 8..15) -> Pf1 ----
#pragma unroll
        for (int r = 0; r < 8; ++r) {
            float v = __builtin_amdgcn_exp2f(aA[8 + r] + aB[8 + r]);
            P1[r] = v; part1 += v;
        }
        s8v Pf1;
        {
            unsigned x0 = pk2(P1[0], P1[1]), x1 = pk2(P1[2], P1[3]);
            unsigned y0 = pk2(P1[4], P1[5]), y1 = pk2(P1[6], P1[7]);
            auto t0 = __builtin_amdgcn_permlane32_swap(x0, y0, false, false);
            auto t1 = __builtin_amdgcn_permlane32_swap(x1, y1, false, false);
            u4 w = { (unsigned)t0[0], (unsigned)t1[0], (unsigned)t0[1], (unsigned)t1[1] };
            Pf1 = *(s8v*)&w;
        }
        lsum += part0 + part1;

        // ---- PV ksl=1 (k-slice offset INSIDE the swizzle XOR — R8 bugfix) ----
        __builtin_amdgcn_s_setprio(1);
#pragma unroll
        for (int dt = 0; dt < 4; ++dt) {
            const int d = dt * 32 + l31;
            s8v Vf = *(const s8v*)&sVt[B][(d * KVBLK + 8 * h + 16) ^ swz32k(d)];
            accO[dt] = __builtin_amdgcn_mfma_f32_32x32x16_bf16(Pf1, Vf, accO[dt], 0, 0, 0);
        }
        __builtin_amdgcn_s_setprio(0);

        __syncthreads();   // next tile resident; this tile's reads done
    };

    for (int tt = 0; tt < TILES; tt += 2) {
        body(std::integral_constant<int, 0>{}, tt);
        body(std::integral_constant<int, 1>{}, tt + 1);
    }

    // ---- epilogue ----
    const float tot = lsum + __shfl_xor(lsum, 32);
    const float inv = 1.f / tot;
#pragma unroll
    for (int r = 0; r < 16; ++r) {
        const int q      = (r & 3) + 8 * (r >> 2) + 4 * h;
        const float invq = __shfl(inv, q, 32);
        float* op = oh + (size_t)(qw0 + q) * DIM + l31;
#pragma unroll
        for (int dt = 0; dt < 4; ++dt)
            op[dt * 32] = accO[dt][r] * invq;
    }
}

// ---------------- fallback (ws too small): proven no-ws kernel ----------------
__global__ __launch_bounds__(256, 2)
void attn_fwd_fb(const float* __restrict__ x, float* __restrict__ out) {
    const int bid  = blockIdx.x;
    const int wg   = (bid & 7) * 256 + (bid >> 3);
    const int head = wg >> 4;
    const int qb   = wg & 15;
    const float* __restrict__ xh = x   + (size_t)head * (NSEQ * DIM);
    float* __restrict__       oh = out + (size_t)head * (NSEQ * DIM);
    const int tid  = threadIdx.x;
    const int lane = tid & 63;
    const int wave = tid >> 6;
    const int l31  = lane & 31;
    const int h    = lane >> 5;
    __shared__ __align__(16) short sK [64 * DIM];
    __shared__ __align__(16) short sVt[DIM * 64];
    const int qw0 = qb * 128 + wave * 32;
    s8v Qf[8];
    {
        const float* qp = xh + (size_t)(qw0 + l31) * DIM + 8 * h;
#pragma unroll
        for (int ks = 0; ks < 8; ++ks) {
            f4 a = *(const f4*)(qp + ks * 16);
            f4 b = *(const f4*)(qp + ks * 16 + 4);
            u4 q = { pk2(a[0] * EC, a[1] * EC), pk2(a[2] * EC, a[3] * EC),
                     pk2(b[0] * EC, b[1] * EC), pk2(b[2] * EC, b[3] * EC) };
            Qf[ks] = *(s8v*)&q;
        }
    }
    f16v accO[4];
#pragma unroll
    for (int dt = 0; dt < 4; ++dt) accO[dt] = (f16v)(0.f);
    float lsum = 0.f;
    const int rw = tid >> 4;
    const int cg = tid & 15;
    f4 ld[8];
    {
        const float* s = xh + (size_t)(4 * rw) * DIM + 8 * cg;
#pragma unroll
        for (int i = 0; i < 4; ++i) {
            ld[2*i]   = *(const f4*)(s + i * DIM);
            ld[2*i+1] = *(const f4*)(s + i * DIM + 4);
        }
    }
    for (int kv0 = 0; kv0 < NSEQ; kv0 += 64) {
#pragma unroll
        for (int i = 0; i < 4; ++i) {
            const int r = 4 * rw + i;
            u4 kv = { pk2(ld[2*i][0],   ld[2*i][1]),   pk2(ld[2*i][2],   ld[2*i][3]),
                      pk2(ld[2*i+1][0], ld[2*i+1][1]), pk2(ld[2*i+1][2], ld[2*i+1][3]) };
            *(u4*)&sK[(r * DIM + 8 * cg) ^ swz(r)] = kv;
        }
#pragma unroll
        for (int j = 0; j < 8; ++j) {
            const int d  = 8 * cg + j;
            const int hi = j >> 2, jj = j & 3;
            u2 vv = { pk2(ld[0 + hi][jj], ld[2 + hi][jj]),
                      pk2(ld[4 + hi][jj], ld[6 + hi][jj]) };
            *(u2*)&sVt[(d * 64 + 4 * rw) ^ swz(d)] = vv;
        }
        __syncthreads();
        f16v accS[2];
        accS[0] = (f16v)(0.f); accS[1] = (f16v)(0.f);
        __builtin_amdgcn_s_setprio(1);
#pragma unroll
        for (int ut = 0; ut < 2; ++ut) {
            const int r    = ut * 32 + l31;
            const int base = r * DIM + 8 * h;
            const int sz   = swz(r);
#pragma unroll
            for (int ks = 0; ks < 8; ++ks) {
                s8v Kf = *(const s8v*)&sK[(base + ks * 16) ^ sz];
                accS[ut] = __builtin_amdgcn_mfma_f32_32x32x16_bf16(
                    Kf, Qf[ks], accS[ut], 0, 0, 0);
            }
        }
        __builtin_amdgcn_s_setprio(0);
        if (kv0 + 64 < NSEQ) {
            const float* s = xh + (size_t)(kv0 + 64 + 4 * rw) * DIM + 8 * cg;
#pragma unroll
            for (int i = 0; i < 4; ++i) {
                ld[2*i]   = *(const f4*)(s + i * DIM);
                ld[2*i+1] = *(const f4*)(s + i * DIM + 4);
            }
        }
        float part = 0.f;
#pragma unroll
        for (int ut = 0; ut < 2; ++ut)
#pragma unroll
            for (int r = 0; r < 16; ++r) {
                float v = __builtin_amdgcn_exp2f(accS[ut][r]);
                accS[ut][r] = v;
                part += v;
            }
        lsum += part;
        s8v Pf[4];
#pragma unroll
        for (int ks = 0; ks < 4; ++ks) {
#define PP(f) accS[(f) >> 4][(f) & 15]
            unsigned pa0 = pk2(PP(8*ks + 0), PP(8*ks + 1));
            unsigned pa1 = pk2(PP(8*ks + 2), PP(8*ks + 3));
            unsigned pb0 = pk2(PP(8*ks + 4), PP(8*ks + 5));
            unsigned pb1 = pk2(PP(8*ks + 6), PP(8*ks + 7));
#undef PP
            auto t0 = __builtin_amdgcn_permlane32_swap(pa0, pb0, false, false);
            auto t1 = __builtin_amdgcn_permlane32_swap(pa1, pb1, false, false);
            u4 w = { (unsigned)t0[0], (unsigned)t1[0], (unsigned)t0[1], (unsigned)t1[1] };
            Pf[ks] = *(s8v*)&w;
        }
        __builtin_amdgcn_s_setprio(1);
#pragma unroll
        for (int dt = 0; dt < 4; ++dt) {
            const int d    = dt * 32 + l31;
            const int base = d * 64 + 8 * h;
            const int sz   = swz(d);
#pragma unroll
            for (int ks = 0; ks < 4; ++ks) {
                s8v Vf = *(const s8v*)&sVt[(base + ks * 16) ^ sz];
                accO[dt] = __builtin_amdgcn_mfma_f32_32x32x16_bf16(
                    Pf[ks], Vf, accO[dt], 0, 0, 0);
            }
        }
        __builtin_amdgcn_s_setprio(0);
        __syncthreads();
    }
    const float tot = lsum + __shfl_xor(lsum, 32);
    const float inv = 1.f / tot;
#pragma unroll
    for (int r = 0; r < 16; ++r) {
        const int q      = (r & 3) + 8 * (r >> 2) + 4 * h;
        const float invq = __shfl(inv, q, 32);
        float* op = oh + (size_t)(qw0 + q) * DIM + l31;
#pragma unroll
        for (int dt = 0; dt < 4; ++dt)
            op[dt * 32] = accO[dt][r] * invq;
    }
}

extern "C" void kernel_launch(void* const* d_in, const int* in_sizes, int n_in,
                              void* d_out, int out_size, void* d_ws, size_t ws_size,
                              hipStream_t stream) {
    const float* x = (const float*)d_in[0];
    float* out     = (float*)d_out;
    const size_t perImg = (size_t)128 * TILES * IMG;            // shorts
    const size_t need   = 2 * perImg * sizeof(short);           // 128 MiB
    if (ws_size >= need) {
        short* wsK = (short*)d_ws;
        short* wsV = wsK + perImg;
        hipLaunchKernelGGL(prepass, dim3(4096), dim3(256), 0, stream, x, wsK, wsV);
        hipLaunchKernelGGL(attn_k32p, dim3(2048), dim3(256), 0, stream, x, wsK, wsV, out);
    } else {
        hipLaunchKernelGGL(attn_fwd_fb, dim3(2048), dim3(256), 0, stream, x, out);
    }
}

// Round 13
// 354.283 us; speedup vs baseline: 1.2322x; 1.0265x over previous
//
#include <hip/hip_runtime.h>
#include <hip/hip_bf16.h>
#include <utility>

// MultiHeadAttention: x (8,16,2048,128) fp32, Q=K=V=x per (b,s) head.
// R13 (= R10/R11/R12 resubmitted after repeated infra failures on a dead
// container): cross-tile pipeline — accS(t) carried in regs across the
// barrier; softmax(t) source-interleaved with QK(t+1) MFMA chain. K staged
// 2 ahead, V 1 ahead, 1 barrier/iter. KVBLK=32, 3 blocks/CU.

#define NSEQ   2048
#define DIM    128
#define KVBLK  32
#define TILES  (NSEQ / KVBLK)       // 64
#define IMG    (KVBLK * DIM)        // 4096 shorts = 8 KB per image
// EC = (1/512) * log2(e): exp(s/512) == exp2(s*EC); folded into Q.
#define EC (1.44269504088896f / 512.0f)

typedef short s8v __attribute__((ext_vector_type(8)));
typedef float f4   __attribute__((ext_vector_type(4)));
typedef float f16v __attribute__((ext_vector_type(16)));
typedef unsigned int u2 __attribute__((ext_vector_type(2)));
typedef unsigned int u4 __attribute__((ext_vector_type(4)));

typedef __attribute__((address_space(1))) const void glob_t;
typedef __attribute__((address_space(3))) void lds_t;

__device__ __forceinline__ unsigned pk2(float a, float b) {
    union { __hip_bfloat162 h; unsigned u; } c;
    c.h = __float22bfloat162_rn(make_float2(a, b));
    return c.u;
}
__device__ __forceinline__ int swz32k(int r) { return ((r & 7) ^ ((r >> 3) & 3)) << 3; }
__device__ __forceinline__ int swz(int r)    { return ((r & 7) ^ ((r >> 3) & 7)) << 3; }

// ---------------- pre-pass: x -> bf16 swizzled 32-row images in ws ----------------
__global__ __launch_bounds__(256)
void prepass(const float* __restrict__ x, short* __restrict__ wsK,
             short* __restrict__ wsV) {
    const int b = blockIdx.x;                   // 4096 blocks, 64 rows = 2 tiles
    const float* src = x + (size_t)b * (64 * DIM);
    short* dK = wsK + (size_t)b * 2 * IMG;
    short* dV = wsV + (size_t)b * 2 * IMG;
    const int rw = threadIdx.x >> 4;
    const int cg = threadIdx.x & 15;
    const int tile = rw >> 3;
    const int ul   = 4 * (rw & 7);

    f4 ld[8];
    const float* s = src + (size_t)(4 * rw) * DIM + 8 * cg;
#pragma unroll
    for (int i = 0; i < 4; ++i) {
        ld[2*i]   = *(const f4*)(s + i * DIM);
        ld[2*i+1] = *(const f4*)(s + i * DIM + 4);
    }
#pragma unroll
    for (int i = 0; i < 4; ++i) {               // K image rows (16B stores)
        const int rl = ul + i;
        u4 kv = { pk2(ld[2*i][0],   ld[2*i][1]),   pk2(ld[2*i][2],   ld[2*i][3]),
                  pk2(ld[2*i+1][0], ld[2*i+1][1]), pk2(ld[2*i+1][2], ld[2*i+1][3]) };
        *(u4*)&dK[tile * IMG + ((rl * DIM + 8 * cg) ^ swz32k(rl))] = kv;
    }
#pragma unroll
    for (int j = 0; j < 8; ++j) {               // Vt image rows (8B stores)
        const int d  = 8 * cg + j;
        const int hi = j >> 2, jj = j & 3;
        u2 vv = { pk2(ld[0 + hi][jj], ld[2 + hi][jj]),
                  pk2(ld[4 + hi][jj], ld[6 + hi][jj]) };
        *(u2*)&dV[tile * IMG + ((d * KVBLK + ul) ^ swz32k(d))] = vv;
    }
}

// ---------------- main kernel: cross-tile pipelined ----------------
__global__ __launch_bounds__(256, 3)
void attn_pipe(const float* __restrict__ x, const short* __restrict__ wsK,
               const short* __restrict__ wsV, float* __restrict__ out) {
    const int bid  = blockIdx.x;                    // 2048 blocks
    const int wg   = (bid & 7) * 256 + (bid >> 3);  // XCD swizzle (2048 % 8 == 0)
    const int head = wg >> 4;
    const int qb   = wg & 15;

    float* __restrict__ oh = out + (size_t)head * (NSEQ * DIM);
    const short* gK = wsK + (size_t)head * TILES * IMG;
    const short* gV = wsV + (size_t)head * TILES * IMG;

    const int tid  = threadIdx.x;
    const int lane = tid & 63;
    const int wave = tid >> 6;
    const int l31  = lane & 31;
    const int h    = lane >> 5;

    __shared__ __align__(16) short sK [2][IMG];   // 16 KB
    __shared__ __align__(16) short sVt[2][IMG];   // 16 KB

    // ---- Q frags (x * EC, bf16) ----
    const int qw0 = qb * 128 + wave * 32;
    s8v Qf[8];
    {
        const float* qp = x + (size_t)head * (NSEQ * DIM)
                            + (size_t)(qw0 + l31) * DIM + 8 * h;
#pragma unroll
        for (int ks = 0; ks < 8; ++ks) {
            f4 a = *(const f4*)(qp + ks * 16);
            f4 b = *(const f4*)(qp + ks * 16 + 4);
            u4 q = { pk2(a[0] * EC, a[1] * EC), pk2(a[2] * EC, a[3] * EC),
                     pk2(b[0] * EC, b[1] * EC), pk2(b[2] * EC, b[3] * EC) };
            Qf[ks] = *(s8v*)&q;
        }
    }

    f16v accO[4];
#pragma unroll
    for (int dt = 0; dt < 4; ++dt) accO[dt] = (f16v)(0.f);
    float lsum = 0.f;

    const int soff = wave * 1024 + lane * 8;
    auto stageK = [&](int b, int t) {
        const short* src = gK + (size_t)t * IMG + soff;
#pragma unroll
        for (int i = 0; i < 2; ++i)
            __builtin_amdgcn_global_load_lds((glob_t*)(src + i * 512),
                (lds_t*)&sK[b][soff + i * 512], 16, 0, 0);
    };
    auto stageV = [&](int b, int t) {
        const short* src = gV + (size_t)t * IMG + soff;
#pragma unroll
        for (int i = 0; i < 2; ++i)
            __builtin_amdgcn_global_load_lds((glob_t*)(src + i * 512),
                (lds_t*)&sVt[b][soff + i * 512], 16, 0, 0);
    };

    const int kbase = l31 * DIM + 8 * h;
    const int ksz   = swz32k(l31);

    // ---- prologue: K0->sK[0], V0->sV[0], K1->sK[1]; QK(0) -> accS0 ----
    stageK(0, 0); stageV(0, 0); stageK(1, 1);
    __syncthreads();

    f16v accS0 = (f16v)(0.f), accS1;
    __builtin_amdgcn_s_setprio(1);
#pragma unroll
    for (int ks = 0; ks < 8; ++ks) {
        s8v Kf = *(const s8v*)&sK[0][(kbase + ks * 16) ^ ksz];
        accS0 = __builtin_amdgcn_mfma_f32_32x32x16_bf16(Kf, Qf[ks], accS0, 0, 0, 0);
    }
    __builtin_amdgcn_s_setprio(0);
    __syncthreads();   // protect sK[0] before body(0) restages it with K(2)

    // tile body: parity P = T&1. Reads accS(aR)=S(T); writes aW=S(T+1).
    // stage K(T+2)->sK[P], V(T+1)->sV[P^1]; QK(T+1) from sK[P^1]; PV(T) from sV[P].
    auto body = [&](auto Pc, int T, f16v& aR, f16v& aW) {
        constexpr int P = decltype(Pc)::value;
        if (T + 2 < TILES) stageK(P, T + 2);
        stageV(P ^ 1, T + 1);

        // ---- QK(T+1) chain interleaved with softmax(T) (independent) ----
        aW = (f16v)(0.f);
        f16v p;
        float part = 0.f;
        __builtin_amdgcn_s_setprio(1);
#pragma unroll
        for (int ks = 0; ks < 8; ++ks) {
            s8v Kf = *(const s8v*)&sK[P ^ 1][(kbase + ks * 16) ^ ksz];
            aW = __builtin_amdgcn_mfma_f32_32x32x16_bf16(Kf, Qf[ks], aW, 0, 0, 0);
            float e0 = __builtin_amdgcn_exp2f(aR[2 * ks]);
            float e1 = __builtin_amdgcn_exp2f(aR[2 * ks + 1]);
            p[2 * ks] = e0; p[2 * ks + 1] = e1;
            part += e0 + e1;
        }
        lsum += part;

        // ---- pack P(T) -> A-frags ----
        s8v Pf0, Pf1;
        {
            unsigned x0 = pk2(p[0], p[1]), x1 = pk2(p[2], p[3]);
            unsigned y0 = pk2(p[4], p[5]), y1 = pk2(p[6], p[7]);
            auto t0 = __builtin_amdgcn_permlane32_swap(x0, y0, false, false);
            auto t1 = __builtin_amdgcn_permlane32_swap(x1, y1, false, false);
            u4 w = { (unsigned)t0[0], (unsigned)t1[0], (unsigned)t0[1], (unsigned)t1[1] };
            Pf0 = *(s8v*)&w;
        }
        {
            unsigned x0 = pk2(p[8], p[9]),  x1 = pk2(p[10], p[11]);
            unsigned y0 = pk2(p[12], p[13]), y1 = pk2(p[14], p[15]);
            auto t0 = __builtin_amdgcn_permlane32_swap(x0, y0, false, false);
            auto t1 = __builtin_amdgcn_permlane32_swap(x1, y1, false, false);
            u4 w = { (unsigned)t0[0], (unsigned)t1[0], (unsigned)t0[1], (unsigned)t1[1] };
            Pf1 = *(s8v*)&w;
        }

        // ---- PV(T) from sV[P] (k-slice offset inside the XOR) ----
#pragma unroll
        for (int dt = 0; dt < 4; ++dt) {
            const int d = dt * 32 + l31;
            s8v Vf0 = *(const s8v*)&sVt[P][(d * KVBLK + 8 * h)      ^ swz32k(d)];
            s8v Vf1 = *(const s8v*)&sVt[P][(d * KVBLK + 8 * h + 16) ^ swz32k(d)];
            accO[dt] = __builtin_amdgcn_mfma_f32_32x32x16_bf16(Pf0, Vf0, accO[dt], 0, 0, 0);
            accO[dt] = __builtin_amdgcn_mfma_f32_32x32x16_bf16(Pf1, Vf1, accO[dt], 0, 0, 0);
        }
        __builtin_amdgcn_s_setprio(0);

        __syncthreads();   // drains DMA; protects all buffers for next iter
    };

    for (int tt = 0; tt < 62; tt += 2) {
        body(std::integral_constant<int, 0>{}, tt,     accS0, accS1);
        body(std::integral_constant<int, 1>{}, tt + 1, accS1, accS0);
    }
    body(std::integral_constant<int, 0>{}, 62, accS0, accS1);

    // ---- tail T=63: softmax(accS1) + PV from sV[1] ----
    {
        f16v p;
        float part = 0.f;
#pragma unroll
        for (int r = 0; r < 16; ++r) {
            float v = __builtin_amdgcn_exp2f(accS1[r]);
            p[r] = v; part += v;
        }
        lsum += part;
        s8v Pf0, Pf1;
        {
            unsigned x0 = pk2(p[0], p[1]), x1 = pk2(p[2], p[3]);
            unsigned y0 = pk2(p[4], p[5]), y1 = pk2(p[6], p[7]);
            auto t0 = __builtin_amdgcn_permlane32_swap(x0, y0, false, false);
            auto t1 = __builtin_amdgcn_permlane32_swap(x1, y1, false, false);
            u4 w = { (unsigned)t0[0], (unsigned)t1[0], (unsigned)t0[1], (unsigned)t1[1] };
            Pf0 = *(s8v*)&w;
        }
        {
            unsigned x0 = pk2(p[8], p[9]),  x1 = pk2(p[10], p[11]);
            unsigned y0 = pk2(p[12], p[13]), y1 = pk2(p[14], p[15]);
            auto t0 = __builtin_amdgcn_permlane32_swap(x0, y0, false, false);
            auto t1 = __builtin_amdgcn_permlane32_swap(x1, y1, false, false);
            u4 w = { (unsigned)t0[0], (unsigned)t1[0], (unsigned)t0[1], (unsigned)t1[1] };
            Pf1 = *(s8v*)&w;
        }
        __builtin_amdgcn_s_setprio(1);
#pragma unroll
        for (int dt = 0; dt < 4; ++dt) {
            const int d = dt * 32 + l31;
            s8v Vf0 = *(const s8v*)&sVt[1][(d * KVBLK + 8 * h)      ^ swz32k(d)];
            s8v Vf1 = *(const s8v*)&sVt[1][(d * KVBLK + 8 * h + 16) ^ swz32k(d)];
            accO[dt] = __builtin_amdgcn_mfma_f32_32x32x16_bf16(Pf0, Vf0, accO[dt], 0, 0, 0);
            accO[dt] = __builtin_amdgcn_mfma_f32_32x32x16_bf16(Pf1, Vf1, accO[dt], 0, 0, 0);
        }
        __builtin_amdgcn_s_setprio(0);
    }

    // ---- epilogue ----
    const float tot = lsum + __shfl_xor(lsum, 32);
    const float inv = 1.f / tot;
#pragma unroll
    for (int r = 0; r < 16; ++r) {
        const int q      = (r & 3) + 8 * (r >> 2) + 4 * h;
        const float invq = __shfl(inv, q, 32);
        float* op = oh + (size_t)(qw0 + q) * DIM + l31;
#pragma unroll
        for (int dt = 0; dt < 4; ++dt)
            op[dt * 32] = accO[dt][r] * invq;
    }
}

// ---------------- fallback (ws too small): proven no-ws kernel ----------------
__global__ __launch_bounds__(256, 2)
void attn_fwd_fb(const float* __restrict__ x, float* __restrict__ out) {
    const int bid  = blockIdx.x;
    const int wg   = (bid & 7) * 256 + (bid >> 3);
    const int head = wg >> 4;
    const int qb   = wg & 15;
    const float* __restrict__ xh = x   + (size_t)head * (NSEQ * DIM);
    float* __restrict__       oh = out + (size_t)head * (NSEQ * DIM);
    const int tid  = threadIdx.x;
    const int lane = tid & 63;
    const int wave = tid >> 6;
    const int l31  = lane & 31;
    const int h    = lane >> 5;
    __shared__ __align__(16) short sK [64 * DIM];
    __shared__ __align__(16) short sVt[DIM * 64];
    const int qw0 = qb * 128 + wave * 32;
    s8v Qf[8];
    {
        const float* qp = xh + (size_t)(qw0 + l31) * DIM + 8 * h;
#pragma unroll
        for (int ks = 0; ks < 8; ++ks) {
            f4 a = *(const f4*)(qp + ks * 16);
            f4 b = *(const f4*)(qp + ks * 16 + 4);
            u4 q = { pk2(a[0] * EC, a[1] * EC), pk2(a[2] * EC, a[3] * EC),
                     pk2(b[0] * EC, b[1] * EC), pk2(b[2] * EC, b[3] * EC) };
            Qf[ks] = *(s8v*)&q;
        }
    }
    f16v accO[4];
#pragma unroll
    for (int dt = 0; dt < 4; ++dt) accO[dt] = (f16v)(0.f);
    float lsum = 0.f;
    const int rw = tid >> 4;
    const int cg = tid & 15;
    f4 ld[8];
    {
        const float* s = xh + (size_t)(4 * rw) * DIM + 8 * cg;
#pragma unroll
        for (int i = 0; i < 4; ++i) {
            ld[2*i]   = *(const f4*)(s + i * DIM);
            ld[2*i+1] = *(const f4*)(s + i * DIM + 4);
        }
    }
    for (int kv0 = 0; kv0 < NSEQ; kv0 += 64) {
#pragma unroll
        for (int i = 0; i < 4; ++i) {
            const int r = 4 * rw + i;
            u4 kv = { pk2(ld[2*i][0],   ld[2*i][1]),   pk2(ld[2*i][2],   ld[2*i][3]),
                      pk2(ld[2*i+1][0], ld[2*i+1][1]), pk2(ld[2*i+1][2], ld[2*i+1][3]) };
            *(u4*)&sK[(r * DIM + 8 * cg) ^ swz(r)] = kv;
        }
#pragma unroll
        for (int j = 0; j < 8; ++j) {
            const int d  = 8 * cg + j;
            const int hi = j >> 2, jj = j & 3;
            u2 vv = { pk2(ld[0 + hi][jj], ld[2 + hi][jj]),
                      pk2(ld[4 + hi][jj], ld[6 + hi][jj]) };
            *(u2*)&sVt[(d * 64 + 4 * rw) ^ swz(d)] = vv;
        }
        __syncthreads();
        f16v accS[2];
        accS[0] = (f16v)(0.f); accS[1] = (f16v)(0.f);
        __builtin_amdgcn_s_setprio(1);
#pragma unroll
        for (int ut = 0; ut < 2; ++ut) {
            const int r    = ut * 32 + l31;
            const int base = r * DIM + 8 * h;
            const int sz   = swz(r);
#pragma unroll
            for (int ks = 0; ks < 8; ++ks) {
                s8v Kf = *(const s8v*)&sK[(base + ks * 16) ^ sz];
                accS[ut] = __builtin_amdgcn_mfma_f32_32x32x16_bf16(
                    Kf, Qf[ks], accS[ut], 0, 0, 0);
            }
        }
        __builtin_amdgcn_s_setprio(0);
        if (kv0 + 64 < NSEQ) {
            const float* s = xh + (size_t)(kv0 + 64 + 4 * rw) * DIM + 8 * cg;
#pragma unroll
            for (int i = 0; i < 4; ++i) {
                ld[2*i]   = *(const f4*)(s + i * DIM);
                ld[2*i+1] = *(const f4*)(s + i * DIM + 4);
            }
        }
        float part = 0.f;
#pragma unroll
        for (int ut = 0; ut < 2; ++ut)
#pragma unroll
            for (int r = 0; r < 16; ++r) {
                float v = __builtin_amdgcn_exp2f(accS[ut][r]);
                accS[ut][r] = v;
                part += v;
            }
        lsum += part;
        s8v Pf[4];
#pragma unroll
        for (int ks = 0; ks < 4; ++ks) {
#define PP(f) accS[(f) >> 4][(f) & 15]
            unsigned pa0 = pk2(PP(8*ks + 0), PP(8*ks + 1));
            unsigned pa1 = pk2(PP(8*ks + 2), PP(8*ks + 3));
            unsigned pb0 = pk2(PP(8*ks + 4), PP(8*ks + 5));
            unsigned pb1 = pk2(PP(8*ks + 6), PP(8*ks + 7));
#undef PP
            auto t0 = __builtin_amdgcn_permlane32_swap(pa0, pb0, false, false);
            auto t1 = __builtin_amdgcn_permlane32_swap(pa1, pb1, false, false);
            u4 w = { (unsigned)t0[0], (unsigned)t1[0], (unsigned)t0[1], (unsigned)t1[1] };
            Pf[ks] = *(s8v*)&w;
        }
        __builtin_amdgcn_s_setprio(1);
#pragma unroll
        for (int dt = 0; dt < 4; ++dt) {
            const int d    = dt * 32 + l31;
            const int base = d * 64 + 8 * h;
            const int sz   = swz(d);
#pragma unroll
            for (int ks = 0; ks < 4; ++ks) {
                s8v Vf = *(const s8v*)&sVt[(base + ks * 16) ^ sz];
                accO[dt] = __builtin_amdgcn_mfma_f32_32x32x16_bf16(
                    Pf[ks], Vf, accO[dt], 0, 0, 0);
            }
        }
        __builtin_amdgcn_s_setprio(0);
        __syncthreads();
    }
    const float tot = lsum + __shfl_xor(lsum, 32);
    const float inv = 1.f / tot;
#pragma unroll
    for (int r = 0; r < 16; ++r) {
        const int q      = (r & 3) + 8 * (r >> 2) + 4 * h;
        const float invq = __shfl(inv, q, 32);
        float* op = oh + (size_t)(qw0 + q) * DIM + l31;
#pragma unroll
        for (int dt = 0; dt < 4; ++dt)
            op[dt * 32] = accO[dt][r] * invq;
    }
}

extern "C" void kernel_launch(void* const* d_in, const int* in_sizes, int n_in,
                              void* d_out, int out_size, void* d_ws, size_t ws_size,
                              hipStream_t stream) {
    const float* x = (const float*)d_in[0];
    float* out     = (float*)d_out;
    const size_t perImg = (size_t)128 * TILES * IMG;            // shorts
    const size_t need   = 2 * perImg * sizeof(short);           // 128 MiB
    if (ws_size >= need) {
        short* wsK = (short*)d_ws;
        short* wsV = wsK + perImg;
        hipLaunchKernelGGL(prepass, dim3(4096), dim3(256), 0, stream, x, wsK, wsV);
        hipLaunchKernelGGL(attn_pipe, dim3(2048), dim3(256), 0, stream, x, wsK, wsV, out);
    } else {
        hipLaunchKernelGGL(attn_fwd_fb, dim3(2048), dim3(256), 0, stream, x, out);
    }
}